// Round 1
// baseline (589.189 us; speedup 1.0000x reference)
//
#include <hip/hip_runtime.h>
#include <hip/hip_bf16.h>

#define BATCH 512
#define NROW  64
#define KDIM  1024
#define NDIM  1024

typedef short bf16x8 __attribute__((ext_vector_type(8)));
typedef float f32x4  __attribute__((ext_vector_type(4)));

// fp32 -> bf16 round-to-nearest-even (bit trick)
__device__ __forceinline__ unsigned f2bf_r(float f) {
  unsigned u = __builtin_bit_cast(unsigned, f);
  return (u + 0x7fffu + ((u >> 16) & 1u)) >> 16;
}
__device__ __forceinline__ unsigned pk2bf(float lo, float hi) {
  return f2bf_r(lo) | (f2bf_r(hi) << 16);
}

// out[m, r, n] = sum_k x[m, r, k] * W[r, k, n] + bias[r, n]
// per r: GEMM M=512 (batch), K=1024, N=1024.
// Block = 128x128 output tile, 256 threads (2x2 waves, each 64x64 via 4x4 MFMA 16x16x32 bf16).
__global__ __launch_bounds__(256) void Group_MLP_kernel(
    const float* __restrict__ x, const float* __restrict__ W,
    const float* __restrict__ bias, float* __restrict__ out) {
  // ---- block mapping: XCD-aware swizzle: nb = blockIdx&7 pins W column-slice per XCD
  const int g  = blockIdx.x;
  const int r  = g >> 5;          // 0..63
  const int mb = (g >> 3) & 3;    // 0..3
  const int nb = g & 7;           // 0..7
  const int m0 = mb * 128;
  const int n0 = nb * 128;

  const int t    = threadIdx.x;
  const int l    = t & 63;
  const int wave = t >> 6;
  const int wm   = wave >> 1, wn = wave & 1;
  const int lm   = l & 15, quad = l >> 4;

  // LDS: fragment-linear chunks of 16 B.
  // A region: chunk p = mt*64 + q*16 + lm  holds  x[m0 + mt*16 + lm][k0 + q*8 .. +7] (bf16)
  // B region: chunk p = nt*64 + quad*16 + lm holds W[k0 + quad*8 .. +7][n0 + nt*16 + lm]
  __shared__ uint4 smem4[1024];   // 16 KiB: A = [0,512), B = [512,1024)
  uint2* s2 = (uint2*)smem4;      // 8 B half-chunks

  // ---- A staging: 4 half-chunks per thread, half-chunk index c = i*256 + t
  const float* gA[4];
  int lcA[4];
  #pragma unroll
  for (int i = 0; i < 4; ++i) {
    int c = i * 256 + t;
    int p = c >> 1;
    int ma  = ((p >> 6) << 4) | (p & 15);                 // row in tile
    int kof = (((p >> 4) & 3) << 3) | ((c & 1) << 2);     // k offset in slab
    gA[i] = x + (size_t)(m0 + ma) * (NROW * KDIM) + r * KDIM + kof;
    lcA[i] = c;
  }

  // ---- B staging: thread loads W[k0+qh*4+j][n0+n4*4 .. +3], j=0..3; register 4x4 transpose
  const int n4 = t & 31, qh = t >> 5;
  const float* gB = W + (size_t)r * (KDIM * NDIM) + (qh * 4) * NDIM + n0 + n4 * 4;
  // half-chunk index = 1024 + p*2 + half,  p = (n4>>2)*64 + (qh>>1)*16 + (n4&3)*4 + cr
  const int bBase = 1024 + (((n4 >> 2) * 64 + ((qh >> 1) & 3) * 16 + (n4 & 3) * 4) << 1) + (qh & 1);
  const int rot   = (n4 + (n4 >> 2)) & 3;   // write-order rotation: 16-way -> ~4-way bank conflicts

  // ---- fragment read indices (16 B chunk units)
  const int aIdx = (wm * 4) * 64 + l;
  const int bIdx = 512 + (wn * 4) * 64 + l;

  f32x4 acc[4][4];
  #pragma unroll
  for (int i = 0; i < 4; ++i)
    #pragma unroll
    for (int j = 0; j < 4; ++j)
      acc[i][j] = {0.f, 0.f, 0.f, 0.f};

  float4 pa[4], pb[4];
  #pragma unroll
  for (int i = 0; i < 4; ++i) pa[i] = *(const float4*)(gA[i]);
  #pragma unroll
  for (int j = 0; j < 4; ++j) pb[j] = *(const float4*)(gB + j * NDIM);

  for (int ks = 0; ks < 32; ++ks) {
    __syncthreads();   // previous iteration's LDS reads done
    // convert + write A (consecutive lanes -> consecutive 8 B: conflict-free)
    #pragma unroll
    for (int i = 0; i < 4; ++i) {
      uint2 v;
      v.x = pk2bf(pa[i].x, pa[i].y);
      v.y = pk2bf(pa[i].z, pa[i].w);
      s2[lcA[i]] = v;
    }
    // convert + transpose + write B
    uint2 ch[4];
    ch[0].x = pk2bf(pb[0].x, pb[1].x); ch[0].y = pk2bf(pb[2].x, pb[3].x);
    ch[1].x = pk2bf(pb[0].y, pb[1].y); ch[1].y = pk2bf(pb[2].y, pb[3].y);
    ch[2].x = pk2bf(pb[0].z, pb[1].z); ch[2].y = pk2bf(pb[2].z, pb[3].z);
    ch[3].x = pk2bf(pb[0].w, pb[1].w); ch[3].y = pk2bf(pb[2].w, pb[3].w);
    #pragma unroll
    for (int c = 0; c < 4; ++c) {
      int cr = (c + rot) & 3;
      uint2 v = ch[0];
      v = (cr == 1) ? ch[1] : v;
      v = (cr == 2) ? ch[2] : v;
      v = (cr == 3) ? ch[3] : v;
      s2[bBase + (cr << 1)] = v;
    }
    __syncthreads();
    // prefetch next K-slab (hidden behind MFMA)
    if (ks < 31) {
      #pragma unroll
      for (int i = 0; i < 4; ++i) { gA[i] += 32; pa[i] = *(const float4*)(gA[i]); }
      gB += 32 * NDIM;
      #pragma unroll
      for (int j = 0; j < 4; ++j) pb[j] = *(const float4*)(gB + j * NDIM);
    }
    // compute: 8 x ds_read_b128 (conflict-free, lane-linear) + 16 MFMA
    bf16x8 af[4], bfr[4];
    #pragma unroll
    for (int i = 0; i < 4; ++i) af[i]  = __builtin_bit_cast(bf16x8, smem4[aIdx + i * 64]);
    #pragma unroll
    for (int j = 0; j < 4; ++j) bfr[j] = __builtin_bit_cast(bf16x8, smem4[bIdx + j * 64]);
    #pragma unroll
    for (int i = 0; i < 4; ++i)
      #pragma unroll
      for (int j = 0; j < 4; ++j)
        acc[i][j] = __builtin_amdgcn_mfma_f32_16x16x32_bf16(af[i], bfr[j], acc[i][j], 0, 0, 0);
  }

  // ---- epilogue: C/D layout col = lane&15, row = quad*4 + reg
  const int nColBase = n0 + wn * 64 + lm;
  const int mRowBase = m0 + wm * 64 + quad * 4;
  #pragma unroll
  for (int j = 0; j < 4; ++j) {
    int n = nColBase + j * 16;
    float bv = bias[r * NDIM + n];
    #pragma unroll
    for (int i = 0; i < 4; ++i) {
      int mr = mRowBase + i * 16;
      #pragma unroll
      for (int v = 0; v < 4; ++v) {
        out[(size_t)(mr + v) * (NROW * NDIM) + r * NDIM + n] = acc[i][j][v] + bv;
      }
    }
  }
}

extern "C" void kernel_launch(void* const* d_in, const int* in_sizes, int n_in,
                              void* d_out, int out_size, void* d_ws, size_t ws_size,
                              hipStream_t stream) {
  const float* x    = (const float*)d_in[0];
  const float* W    = (const float*)d_in[1];
  const float* bias = (const float*)d_in[2];
  float* out        = (float*)d_out;
  dim3 grid(64 * 4 * 8), block(256);
  hipLaunchKernelGGL(Group_MLP_kernel, grid, block, 0, stream, x, W, bias, out);
}

// Round 2
// 580.535 us; speedup vs baseline: 1.0149x; 1.0149x over previous
//
#include <hip/hip_runtime.h>
#include <hip/hip_bf16.h>

#define NROW  64
#define KDIM  1024
#define NDIM  1024

typedef short bf16x8 __attribute__((ext_vector_type(8)));
typedef float f32x4  __attribute__((ext_vector_type(4)));

// fp32 -> bf16 round-half-up, two at once: (u + 0x8000) >> 16, packed with one v_perm_b32.
// sel 0x07060302: result bytes [0,1] = src1 (lo) bytes 2,3 ; [2,3] = src0 (hi) bytes 2,3.
__device__ __forceinline__ unsigned pk2bf(float lo, float hi) {
  unsigned ulo = __builtin_bit_cast(unsigned, lo) + 0x8000u;
  unsigned uhi = __builtin_bit_cast(unsigned, hi) + 0x8000u;
  return __builtin_amdgcn_perm(uhi, ulo, 0x07060302u);
}

// out[m, r, n] = sum_k x[m, r, k] * W[r, k, n] + bias[r, n]
// per r: GEMM M=512 (batch), K=1024, N=1024.
// Block = 128x128 output tile, 256 threads (2x2 waves, each 64x64 via 4x4 MFMA 16x16x32 bf16).
__global__ __launch_bounds__(256) void Group_MLP_kernel(
    const float* __restrict__ x, const float* __restrict__ W,
    const float* __restrict__ bias, float* __restrict__ out) {
  // ---- block mapping: XCD-aware swizzle: nb = blockIdx&7 pins W column-slice per XCD
  const int g  = blockIdx.x;
  const int r  = g >> 5;          // 0..63
  const int mb = (g >> 3) & 3;    // 0..3
  const int nb = g & 7;           // 0..7
  const int m0 = mb * 128;
  const int n0 = nb * 128;

  const int t    = threadIdx.x;
  const int l    = t & 63;
  const int wave = t >> 6;
  const int wm   = wave >> 1, wn = wave & 1;
  const int lm   = l & 15, quad = l >> 4;

  // LDS: fragment-linear chunks of 16 B.
  // A region: logical chunk p = mt*64 + q*16 + lm  holds  x[m0 + mt*16 + lm][k0 + q*8 .. +7]
  // B region: logical chunk p = nt*64 + quad*16 + lm holds W[k0 + quad*8 .. +7][n0 + nt*16 + lm]
  //           stored at PHYSICAL chunk p ^ ((p>>6)&7)  (XOR swizzle -> conflict-free writes)
  __shared__ uint4 smem4[1024];   // 16 KiB: A = [0,512), B = [512,1024)
  uint2* s2 = (uint2*)smem4;      // 8 B half-chunks

  // ---- A staging: 4 half-chunks per thread, half-chunk index c = i*256 + t (linear, conflict-free)
  const float* gA[4];
  int lcA[4];
  #pragma unroll
  for (int i = 0; i < 4; ++i) {
    int c = i * 256 + t;
    int p = c >> 1;
    int ma  = ((p >> 6) << 4) | (p & 15);                 // row in tile
    int kof = (((p >> 4) & 3) << 3) | ((c & 1) << 2);     // k offset in slab
    gA[i] = x + (size_t)(m0 + ma) * (NROW * KDIM) + r * KDIM + kof;
    lcA[i] = c;
  }

  // ---- B staging: thread loads W[k0+qh*4+j][n0+n4*4 .. +3], j=0..3; register 4x4 transpose
  const int n4 = t & 31, qh = t >> 5;
  const float* gB = W + (size_t)r * (KDIM * NDIM) + (qh * 4) * NDIM + n0 + n4 * 4;
  // logical chunk for (n = n4*4 + c, kq = qh>>1): p = baseP + c
  const int baseP  = (n4 >> 2) * 64 + ((qh >> 1) & 3) * 16 + (n4 & 3) * 4;
  const int swBase = baseP ^ (n4 >> 2);        // XOR swizzle ((p>>6)&7 == n4>>2, c-independent)
  const int hB     = qh & 1;                   // which 8B half of the 16B chunk

  // ---- fragment read indices (16 B physical chunk units)
  int aIdx[4], bIdx[4];
  #pragma unroll
  for (int i = 0; i < 4; ++i) aIdx[i] = (wm * 4 + i) * 64 + l;
  #pragma unroll
  for (int j = 0; j < 4; ++j) {
    int grp = wn * 4 + j;
    bIdx[j] = 512 + grp * 64 + (l ^ grp);      // physical chunk of logical grp*64 + l
  }

  f32x4 acc[4][4];
  #pragma unroll
  for (int i = 0; i < 4; ++i)
    #pragma unroll
    for (int j = 0; j < 4; ++j)
      acc[i][j] = {0.f, 0.f, 0.f, 0.f};

  float4 pa[4], pb[4];
  #pragma unroll
  for (int i = 0; i < 4; ++i) pa[i] = *(const float4*)(gA[i]);
  #pragma unroll
  for (int j = 0; j < 4; ++j) pb[j] = *(const float4*)(gB + j * NDIM);

  for (int ks = 0; ks < 32; ++ks) {
    __syncthreads();   // previous iteration's LDS reads done
    // convert + write A (consecutive lanes -> consecutive 8 B: conflict-free)
    #pragma unroll
    for (int i = 0; i < 4; ++i) {
      uint2 v;
      v.x = pk2bf(pa[i].x, pa[i].y);
      v.y = pk2bf(pa[i].z, pa[i].w);
      s2[lcA[i]] = v;
    }
    // convert + transpose + write B (swizzled addresses, natural data order, conflict-free)
    uint2 ch[4];
    ch[0].x = pk2bf(pb[0].x, pb[1].x); ch[0].y = pk2bf(pb[2].x, pb[3].x);
    ch[1].x = pk2bf(pb[0].y, pb[1].y); ch[1].y = pk2bf(pb[2].y, pb[3].y);
    ch[2].x = pk2bf(pb[0].z, pb[1].z); ch[2].y = pk2bf(pb[2].z, pb[3].z);
    ch[3].x = pk2bf(pb[0].w, pb[1].w); ch[3].y = pk2bf(pb[2].w, pb[3].w);
    #pragma unroll
    for (int c = 0; c < 4; ++c) {
      s2[1024 + ((swBase ^ c) << 1) + hB] = ch[c];
    }
    __syncthreads();
    // prefetch next K-slab (hidden behind MFMA)
    if (ks < 31) {
      #pragma unroll
      for (int i = 0; i < 4; ++i) { gA[i] += 32; pa[i] = *(const float4*)(gA[i]); }
      gB += 32 * NDIM;
      #pragma unroll
      for (int j = 0; j < 4; ++j) pb[j] = *(const float4*)(gB + j * NDIM);
    }
    // compute: 8 x ds_read_b128 (conflict-free) + 16 MFMA
    bf16x8 af[4], bfr[4];
    #pragma unroll
    for (int i = 0; i < 4; ++i) af[i]  = __builtin_bit_cast(bf16x8, smem4[aIdx[i]]);
    #pragma unroll
    for (int j = 0; j < 4; ++j) bfr[j] = __builtin_bit_cast(bf16x8, smem4[bIdx[j]]);
    #pragma unroll
    for (int i = 0; i < 4; ++i)
      #pragma unroll
      for (int j = 0; j < 4; ++j)
        acc[i][j] = __builtin_amdgcn_mfma_f32_16x16x32_bf16(af[i], bfr[j], acc[i][j], 0, 0, 0);
  }

  // ---- epilogue: C/D layout col = lane&15, row = quad*4 + reg
  const int nColBase = n0 + wn * 64 + lm;
  const int mRowBase = m0 + wm * 64 + quad * 4;
  #pragma unroll
  for (int j = 0; j < 4; ++j) {
    int n = nColBase + j * 16;
    float bv = bias[r * NDIM + n];
    #pragma unroll
    for (int i = 0; i < 4; ++i) {
      int mr = mRowBase + i * 16;
      #pragma unroll
      for (int v = 0; v < 4; ++v) {
        out[(size_t)(mr + v) * (NROW * NDIM) + r * NDIM + n] = acc[i][j][v] + bv;
      }
    }
  }
}

extern "C" void kernel_launch(void* const* d_in, const int* in_sizes, int n_in,
                              void* d_out, int out_size, void* d_ws, size_t ws_size,
                              hipStream_t stream) {
  const float* x    = (const float*)d_in[0];
  const float* W    = (const float*)d_in[1];
  const float* bias = (const float*)d_in[2];
  float* out        = (float*)d_out;
  dim3 grid(64 * 4 * 8), block(256);
  hipLaunchKernelGGL(Group_MLP_kernel, grid, block, 0, stream, x, W, bias, out);
}